// Round 4
// baseline (2353.698 us; speedup 1.0000x reference)
//
#include <hip/hip_runtime.h>
#include <cstdint>

// Instant-NGP hash encoding + 2-layer MLP, fully fused, all-fp32.
// N=524288 pts, L=16 levels, T=2^19 table, F=8 feats -> enc dim 128.
// Layer1: 128->128 + LeakyReLU(0.01). Layer2: 128->256.

#define NPTS        524288
#define NLEVELS     16
#define TSIZE       (1u << 19)
#define TMASK       (TSIZE - 1u)
#define FFEAT       8
#define PTS_BLK     32          // points per block
#define PITCH       132         // 128 + 4 pad floats (16B-aligned rows, breaks bank stride)

// floor(16 * 1.5^l) computed exactly; all values fp32-exact integers.
__constant__ float c_res[NLEVELS] = {
    16.f, 24.f, 36.f, 54.f, 81.f, 121.f, 182.f, 273.f,
    410.f, 615.f, 922.f, 1383.f, 2075.f, 3113.f, 4670.f, 7006.f
};

__global__ __launch_bounds__(256, 4)
void ngp_fused_kernel(const float* __restrict__ z,
                      const float* __restrict__ tables,
                      const float* __restrict__ W1,
                      const float* __restrict__ b1,
                      const float* __restrict__ W2,
                      const float* __restrict__ b2,
                      float* __restrict__ out)
{
    __shared__ __align__(16) float enc[PTS_BLK][PITCH];   // encoding [32][128(+4)]
    __shared__ __align__(16) float hb[PTS_BLK][PITCH];    // hidden   [32][128(+4)]
    __shared__ float zs[PTS_BLK * 3];

    const int t     = threadIdx.x;        // 0..255
    const int blk   = blockIdx.x;
    const int pbase = blk * PTS_BLK;

    // ---- stage z for this block's 32 points ----
    if (t < PTS_BLK * 3) {
        zs[t] = z[(size_t)pbase * 3 + t];
    }
    __syncthreads();

    // ---- Phase A: hash encoding. 32 pts x 16 levels = 512 tasks, 2/thread ----
    #pragma unroll
    for (int ti = 0; ti < 2; ++ti) {
        const int task = t + ti * 256;
        const int p = task & 31;       // point within block
        const int l = task >> 5;       // level 0..15

        const float res = c_res[l];
        const float xs0 = zs[p * 3 + 0] * res;
        const float xs1 = zs[p * 3 + 1] * res;
        const float xs2 = zs[p * 3 + 2] * res;
        const float f0 = floorf(xs0), f1 = floorf(xs1), f2 = floorf(xs2);
        const float w0 = xs0 - f0, w1 = xs1 - f1, w2 = xs2 - f2;
        const uint32_t x0 = (uint32_t)f0;
        const uint32_t x1 = (uint32_t)f1;
        const uint32_t x2 = (uint32_t)f2;

        const float* tab = tables + (size_t)l * (size_t)(TSIZE * FFEAT);

        float acc0 = 0.f, acc1 = 0.f, acc2 = 0.f, acc3 = 0.f;
        float acc4 = 0.f, acc5 = 0.f, acc6 = 0.f, acc7 = 0.f;

        #pragma unroll
        for (int c = 0; c < 8; ++c) {
            const uint32_t dx = (c >> 2) & 1u;   // dim0 bit (matches OFFS)
            const uint32_t dy = (c >> 1) & 1u;   // dim1 bit
            const uint32_t dz = c & 1u;          // dim2 bit

            // uint32 wraparound hash: primes {1, 2654435761, 805459861}
            const uint32_t hx = (x0 + dx) * 1u;
            const uint32_t hy = (x1 + dy) * 2654435761u;
            const uint32_t hz = (x2 + dz) * 805459861u;
            const uint32_t idx = (hx ^ hy ^ hz) & TMASK;

            const float4* fp = reinterpret_cast<const float4*>(tab + ((size_t)idx << 3));
            const float4 fa = fp[0];
            const float4 fb = fp[1];

            // trilinear weight, same multiply order as reference prod(-1)
            const float cwx = dx ? w0 : (1.0f - w0);
            const float cwy = dy ? w1 : (1.0f - w1);
            const float cwz = dz ? w2 : (1.0f - w2);
            const float cw = (cwx * cwy) * cwz;

            acc0 = fmaf(cw, fa.x, acc0);
            acc1 = fmaf(cw, fa.y, acc1);
            acc2 = fmaf(cw, fa.z, acc2);
            acc3 = fmaf(cw, fa.w, acc3);
            acc4 = fmaf(cw, fb.x, acc4);
            acc5 = fmaf(cw, fb.y, acc5);
            acc6 = fmaf(cw, fb.z, acc6);
            acc7 = fmaf(cw, fb.w, acc7);
        }

        float* e = &enc[p][l * FFEAT];
        reinterpret_cast<float4*>(e)[0] = make_float4(acc0, acc1, acc2, acc3);
        reinterpret_cast<float4*>(e)[1] = make_float4(acc4, acc5, acc6, acc7);
    }
    __syncthreads();

    // ---- Phase B: layer 1 (128 -> 128) + bias + LeakyReLU(0.01) ----
    // thread tile: 2 points (px, px+16) x 8 cols (cy*8 .. cy*8+7)
    const int px   = t & 15;     // 0..15
    const int cy   = t >> 4;     // 0..15
    const int colb = cy * 8;

    {
        float a0[8], a1[8];
        #pragma unroll
        for (int j = 0; j < 8; ++j) { a0[j] = 0.f; a1[j] = 0.f; }

        #pragma unroll 4
        for (int k = 0; k < 128; k += 4) {
            const float4 e0 = *reinterpret_cast<const float4*>(&enc[px][k]);
            const float4 e1 = *reinterpret_cast<const float4*>(&enc[px + 16][k]);
            #pragma unroll
            for (int j = 0; j < 8; ++j) {
                const float4 wv = *reinterpret_cast<const float4*>(&W1[(size_t)(colb + j) * 128 + k]);
                a0[j] = fmaf(e0.x, wv.x, a0[j]);
                a0[j] = fmaf(e0.y, wv.y, a0[j]);
                a0[j] = fmaf(e0.z, wv.z, a0[j]);
                a0[j] = fmaf(e0.w, wv.w, a0[j]);
                a1[j] = fmaf(e1.x, wv.x, a1[j]);
                a1[j] = fmaf(e1.y, wv.y, a1[j]);
                a1[j] = fmaf(e1.z, wv.z, a1[j]);
                a1[j] = fmaf(e1.w, wv.w, a1[j]);
            }
        }

        #pragma unroll
        for (int j = 0; j < 8; ++j) {
            const float bj = b1[colb + j];
            float v0 = a0[j] + bj;
            float v1 = a1[j] + bj;
            v0 = (v0 >= 0.f) ? v0 : 0.01f * v0;
            v1 = (v1 >= 0.f) ? v1 : 0.01f * v1;
            hb[px][colb + j] = v0;
            hb[px + 16][colb + j] = v1;
        }
    }
    __syncthreads();

    // ---- Phase C: layer 2 (128 -> 256) + bias, write output ----
    #pragma unroll
    for (int half = 0; half < 2; ++half) {
        float c0[8], c1[8];
        #pragma unroll
        for (int j = 0; j < 8; ++j) { c0[j] = 0.f; c1[j] = 0.f; }

        const int ocolb = half * 128 + colb;

        #pragma unroll 4
        for (int k = 0; k < 128; k += 4) {
            const float4 h0 = *reinterpret_cast<const float4*>(&hb[px][k]);
            const float4 h1 = *reinterpret_cast<const float4*>(&hb[px + 16][k]);
            #pragma unroll
            for (int j = 0; j < 8; ++j) {
                const float4 wv = *reinterpret_cast<const float4*>(&W2[(size_t)(ocolb + j) * 128 + k]);
                c0[j] = fmaf(h0.x, wv.x, c0[j]);
                c0[j] = fmaf(h0.y, wv.y, c0[j]);
                c0[j] = fmaf(h0.z, wv.z, c0[j]);
                c0[j] = fmaf(h0.w, wv.w, c0[j]);
                c1[j] = fmaf(h1.x, wv.x, c1[j]);
                c1[j] = fmaf(h1.y, wv.y, c1[j]);
                c1[j] = fmaf(h1.z, wv.z, c1[j]);
                c1[j] = fmaf(h1.w, wv.w, c1[j]);
            }
        }

        #pragma unroll
        for (int j = 0; j < 8; ++j) {
            const float bj = b2[ocolb + j];
            c0[j] += bj;
            c1[j] += bj;
        }

        float* o0 = out + (size_t)(pbase + px) * 256 + ocolb;
        float* o1 = out + (size_t)(pbase + px + 16) * 256 + ocolb;
        reinterpret_cast<float4*>(o0)[0] = make_float4(c0[0], c0[1], c0[2], c0[3]);
        reinterpret_cast<float4*>(o0)[1] = make_float4(c0[4], c0[5], c0[6], c0[7]);
        reinterpret_cast<float4*>(o1)[0] = make_float4(c1[0], c1[1], c1[2], c1[3]);
        reinterpret_cast<float4*>(o1)[1] = make_float4(c1[4], c1[5], c1[6], c1[7]);
    }
}

extern "C" void kernel_launch(void* const* d_in, const int* in_sizes, int n_in,
                              void* d_out, int out_size, void* d_ws, size_t ws_size,
                              hipStream_t stream) {
    (void)in_sizes; (void)n_in; (void)d_ws; (void)ws_size; (void)out_size;

    const float* z      = (const float*)d_in[0];   // [524288, 3]
    const float* tables = (const float*)d_in[1];   // [16, 2^19, 8]
    const float* W1     = (const float*)d_in[2];   // [128, 128]
    const float* b1     = (const float*)d_in[3];   // [128]
    const float* W2     = (const float*)d_in[4];   // [256, 128]
    const float* b2     = (const float*)d_in[5];   // [256]
    float* out          = (float*)d_out;           // [524288, 256]

    const int nblocks = NPTS / PTS_BLK;            // 16384
    ngp_fused_kernel<<<dim3(nblocks), dim3(256), 0, stream>>>(
        z, tables, W1, b1, W2, b2, out);
}